// Round 9
// baseline (55.179 us; speedup 1.0000x reference)
//
#include <hip/hip_runtime.h>

#define SEQ  2048
#define NSEG 24

typedef __bf16 bf16x8 __attribute__((ext_vector_type(8)));
typedef float  f32x4  __attribute__((ext_vector_type(4)));
typedef unsigned short u16x4 __attribute__((ext_vector_type(4)));
typedef unsigned short ushort8 __attribute__((ext_vector_type(8)));
typedef unsigned long long u64;

// d_ws layout (bytes): [0,256) zero row; then bf16 B-fragment blocks
#define WS_K 256
#define WS_V (256 + 196608)
#define WS_Q (256 + 393216)
#define WS_O (256 + 393216 + 8192)

__device__ __forceinline__ float4 ld4(const float* __restrict__ p) {
    return *reinterpret_cast<const float4*>(p);
}
__device__ __forceinline__ unsigned short f2bf(float f) {
    unsigned u = __float_as_uint(f);
    unsigned r = u + 0x7FFFu + ((u >> 16) & 1u);   // RNE
    return (unsigned short)(r >> 16);
}

// ---------------- prep: weights -> bf16 B-fragment layout in ws ----------------
__global__ __launch_bounds__(256) void prep_ws(
    const float* __restrict__ Wk, const float* __restrict__ Wv,
    const float* __restrict__ Wq, const float* __restrict__ Wo,
    char* __restrict__ ws)
{
    const int tid = blockIdx.x * 256 + threadIdx.x;
    if (tid < 64) ((float*)ws)[tid] = 0.0f;
    const float* W; char* base; int it = tid;
    if      (it < 12288) { W = Wk; base = ws + WS_K; }
    else if (it < 24576) { W = Wv; base = ws + WS_V; it -= 12288; }
    else if (it < 25088) { W = Wq; base = ws + WS_Q; it -= 24576; }
    else if (it < 25600) { W = Wo; base = ws + WS_O; it -= 25088; }
    else return;
    const int lc = it & 15, lg = (it >> 4) & 3, nt = (it >> 6) & 3, sh = it >> 8;
    const int col = nt * 16 + lc;
    const int k0  = sh * 32 + lg * 8;
    ushort8 v;
#pragma unroll
    for (int j = 0; j < 8; ++j) v[j] = f2bf(W[(size_t)(k0 + j) * 64 + col]);
    *(ushort8*)(base + (size_t)it * 16) = v;
}

// ---------------- main: 2 tiles/block, both gathers issued up-front -----------
// LDS: A-frags bf16 [24 seg][2048B] = 49152 ; idx[2][24][16] = 3072 (aliased by
// gatep 256 + gateL 64 after gather issue). Epilogue aliases A region:
// gv bf16 @ L+0 ; out-stage fp32 @ L+4096.
#define L_IDX  49152
#define LDS_BYTES 52224

__global__ __launch_bounds__(256, 2) void engram_main(
    const int*   __restrict__ tok,
    const float* __restrict__ hidden,
    const float* __restrict__ tab2, const int* __restrict__ mul2,
    const float* __restrict__ tab3, const int* __restrict__ mul3,
    const float* __restrict__ tab4, const int* __restrict__ mul4,
    const float* __restrict__ bq, const float* __restrict__ bk,
    const float* __restrict__ bv, const float* __restrict__ bo,
    const char*  __restrict__ ws,
    float* __restrict__ out, float* __restrict__ gate_out)
{
    __shared__ __align__(16) char L[LDS_BYTES];
    int*   idxL  = (int*)  (L + L_IDX);          // [2][24][16]
    float* gatep = (float*)(L + L_IDX);          // alias: idx dead after issue
    float* gateL = (float*)(L + L_IDX + 256);

    const int t     = threadIdx.x;
    const int pbase = blockIdx.x * 32;

    // ---- hash phase: all 256 threads, 2 tiles x 8 heads x 16 rows -------------
    {
        const int tile = t >> 7;
        const int h = (t & 127) >> 4, r0 = t & 15;
        const int pos = pbase + tile * 16 + r0;
        const int s   = pos & (SEQ - 1);
        const int b   = pos >> 11;
        const int* tr = tok + (size_t)b * SEQ;
        const u64 t3 = (u64)tr[s];
        const u64 t2 = (s >= 1) ? (u64)tr[s - 1] : 0ull;
        const u64 t1 = (s >= 2) ? (u64)tr[s - 2] : 0ull;
        const u64 t0 = (s >= 3) ? (u64)tr[s - 3] : 0ull;
        int* ix = idxL + tile * 384;
        { u64 m = (u64)mul2[h];
          u64 hh = (t2 * m + t3) % 100003ull;
          ix[h * 16 + r0] = (s >= 1) ? (int)hh : -1; }
        { u64 m = (u64)mul3[h];
          u64 hh = (t1 * m + t2) % 100019ull;
          hh = (hh * m + t3) % 100019ull;
          ix[(8 + h) * 16 + r0] = (s >= 2) ? (int)hh : -1; }
        { u64 m = (u64)mul4[h];
          u64 hh = (t0 * m + t1) % 100043ull;
          hh = (hh * m + t2) % 100043ull;
          hh = (hh * m + t3) % 100043ull;
          ix[(16 + h) * 16 + r0] = (s >= 3) ? (int)hh : -1; }
    }
    __syncthreads();

    // ---- gather issue: thread (r = t>>4, c = t&15); both tiles up-front -------
    const int r     = t >> 4;
    const int c     = t & 15;
    const int fhalf = c >> 3, flg = (c >> 1) & 3, piece = c & 1;
    const int wb = fhalf * 1024 + flg * 256 + ((r ^ flg) << 4) + piece * 8;

    float4 R1[NSEG], R2[NSEG];
    auto gissue = [&](int tile, float4* R) {
#pragma unroll
        for (int s = 0; s < NSEG; ++s) {
            const int ix = idxL[tile * 384 + s * 16 + r];
            const int ni = s >> 3, h = s & 7;
            const float* tabp; int prime;
            if (ni == 0)      { tabp = tab2; prime = 100003; }
            else if (ni == 1) { tabp = tab3; prime = 100019; }
            else              { tabp = tab4; prime = 100043; }
            float4 z; z.x = z.y = z.z = z.w = 0.0f;
            R[s] = (ix < 0) ? z : ld4(tabp + ((size_t)h * prime + ix) * 64 + c * 4);
        }
    };
    auto wbuf = [&](const float4* R) {
#pragma unroll
        for (int s = 0; s < NSEG; ++s) {
            u16x4 e;
            e[0] = f2bf(R[s].x); e[1] = f2bf(R[s].y);
            e[2] = f2bf(R[s].z); e[3] = f2bf(R[s].w);
            *(u16x4*)(L + s * 2048 + wb) = e;
        }
    };

    gissue(0, R1);
    gissue(1, R2);          // tile-1 gathers ride in flight across tile-0 work

    // ---- compute/epilogue roles ----------------------------------------------
    const int w   = t >> 6;
    const int lam = t & 63;
    const int lg  = lam >> 4, lc = lam & 15;
    const int fo  = lg * 256 + lc * 16;
    const int ra  = lg * 256 + (((lc ^ lg) & 15) << 4);
    const int cc  = w * 16 + lc;
    const float bkc = bk[cc], bvc = bv[cc], bqc = bq[cc], boc = bo[cc];

    char*  Lgv  = L;
    float* Lout = (float*)(L + 4096);
    const char* pK = ws + WS_K;
    const char* pV = ws + WS_V;
#define LOADB(s, k0_, k1_, v0_, v1_)                                          \
    { const char* bk_ = pK + (size_t)(s) * 8192 + w * 1024 + fo;              \
      const char* bv_ = pV + (size_t)(s) * 8192 + w * 1024 + fo;              \
      k0_ = *(const bf16x8*)(bk_);        k1_ = *(const bf16x8*)(bk_ + 4096); \
      v0_ = *(const bf16x8*)(bv_);        v1_ = *(const bf16x8*)(bv_ + 4096); }

    auto tileCompute = [&](int tile) {
        f32x4 kacc = {0.f,0.f,0.f,0.f}, vacc = {0.f,0.f,0.f,0.f};
        bf16x8 ck0, ck1, cv0, cv1, nk0, nk1, nv0, nv1;
        LOADB(0, ck0, ck1, cv0, cv1);
        LOADB(1, nk0, nk1, nv0, nv1);

        const float* hp = hidden + (size_t)(pbase + tile * 16 + lc) * 64 + lg * 8;
        const float4 h0a = ld4(hp),      h0b = ld4(hp + 4);
        const float4 h1a = ld4(hp + 32), h1b = ld4(hp + 36);

#pragma unroll
        for (int s = 0; s < NSEG; ++s) {
            const bf16x8 a0 = *(const bf16x8*)(L + s * 2048 +        ra);
            const bf16x8 a1 = *(const bf16x8*)(L + s * 2048 + 1024 + ra);
            kacc = __builtin_amdgcn_mfma_f32_16x16x32_bf16(a0, ck0, kacc, 0, 0, 0);
            kacc = __builtin_amdgcn_mfma_f32_16x16x32_bf16(a1, ck1, kacc, 0, 0, 0);
            vacc = __builtin_amdgcn_mfma_f32_16x16x32_bf16(a0, cv0, vacc, 0, 0, 0);
            vacc = __builtin_amdgcn_mfma_f32_16x16x32_bf16(a1, cv1, vacc, 0, 0, 0);
            ck0 = nk0; ck1 = nk1; cv0 = nv0; cv1 = nv1;
            if (s + 2 < NSEG) LOADB(s + 2, nk0, nk1, nv0, nv1);
        }

#pragma unroll
        for (int i = 0; i < 4; ++i) { kacc[i] += bkc; vacc[i] += bvc; }

        // q = hidden @ Wq (this wave's quarter)
        bf16x8 qa0, qa1;
        qa0[0]=(__bf16)h0a.x; qa0[1]=(__bf16)h0a.y; qa0[2]=(__bf16)h0a.z; qa0[3]=(__bf16)h0a.w;
        qa0[4]=(__bf16)h0b.x; qa0[5]=(__bf16)h0b.y; qa0[6]=(__bf16)h0b.z; qa0[7]=(__bf16)h0b.w;
        qa1[0]=(__bf16)h1a.x; qa1[1]=(__bf16)h1a.y; qa1[2]=(__bf16)h1a.z; qa1[3]=(__bf16)h1a.w;
        qa1[4]=(__bf16)h1b.x; qa1[5]=(__bf16)h1b.y; qa1[6]=(__bf16)h1b.z; qa1[7]=(__bf16)h1b.w;
        f32x4 qacc = {0.f,0.f,0.f,0.f};
        {
            const char* bq_ = ws + WS_Q + w * 1024 + fo;
            const bf16x8 qb0 = *(const bf16x8*)(bq_);
            const bf16x8 qb1 = *(const bf16x8*)(bq_ + 4096);
            qacc = __builtin_amdgcn_mfma_f32_16x16x32_bf16(qa0, qb0, qacc, 0, 0, 0);
            qacc = __builtin_amdgcn_mfma_f32_16x16x32_bf16(qa1, qb1, qacc, 0, 0, 0);
        }
        float gp4[4];
#pragma unroll
        for (int i = 0; i < 4; ++i) {
            float p = (qacc[i] + bqc) * kacc[i];
            p += __shfl_xor(p, 1, 64);
            p += __shfl_xor(p, 2, 64);
            p += __shfl_xor(p, 4, 64);
            p += __shfl_xor(p, 8, 64);
            gp4[i] = p;
        }
        if (lc == 0) {
#pragma unroll
            for (int i = 0; i < 4; ++i) gatep[w * 16 + lg * 4 + i] = gp4[i];
        }
        __syncthreads();             // A-frag reads done; gatep visible

        if (t < 16) {
            const float s  = gatep[t] + gatep[16 + t] + gatep[32 + t] + gatep[48 + t];
            const float gt = 1.0f / (1.0f + expf(-s * 0.125f));
            gateL[t] = gt;
            gate_out[pbase + tile * 16 + t] = gt;
        }
        __syncthreads();             // gate visible; A region free

        // gv = gate * v (bf16, XOR-swizzled) into A region
#pragma unroll
        for (int i = 0; i < 4; ++i) {
            const int row = lg * 4 + i;
            const float gvv = gateL[row] * vacc[i];
            *(unsigned short*)(Lgv + row * 128 + ((w * 32 + lc * 2) ^ ((row & 7) << 4))) = f2bf(gvv);
        }
        __syncthreads();

        // out = gv @ Wo + bo -> stage fp32 in LDS, coalesced store
        f32x4 oacc = {0.f,0.f,0.f,0.f};
        {
            const char* bo_ = ws + WS_O + w * 1024 + fo;
            const bf16x8 ob0 = *(const bf16x8*)(bo_);
            const bf16x8 ob1 = *(const bf16x8*)(bo_ + 4096);
            const bf16x8 ga0 = *(const bf16x8*)(Lgv + lc * 128 + ((lg * 16)      ^ ((lc & 7) << 4)));
            const bf16x8 ga1 = *(const bf16x8*)(Lgv + lc * 128 + ((64 + lg * 16) ^ ((lc & 7) << 4)));
            oacc = __builtin_amdgcn_mfma_f32_16x16x32_bf16(ga0, ob0, oacc, 0, 0, 0);
            oacc = __builtin_amdgcn_mfma_f32_16x16x32_bf16(ga1, ob1, oacc, 0, 0, 0);
        }
#pragma unroll
        for (int i = 0; i < 4; ++i)
            Lout[(lg * 4 + i) * 64 + cc] = oacc[i] + boc;
        __syncthreads();

        const float4 o4 = *(const float4*)(Lout + r * 64 + c * 4);
        *reinterpret_cast<float4*>(out + (size_t)(pbase + tile * 16 + r) * 64 + c * 4) = o4;
    };

    // ---- tile 0 ---------------------------------------------------------------
    wbuf(R1);                        // counted wait: R2's 24 loads stay in flight
    __syncthreads();
    tileCompute(0);
    __syncthreads();                 // all tile-0 LDS reads complete

    // ---- tile 1 ---------------------------------------------------------------
    wbuf(R2);                        // data long since landed
    __syncthreads();
    tileCompute(1);
}

extern "C" void kernel_launch(void* const* d_in, const int* in_sizes, int n_in,
                              void* d_out, int out_size, void* d_ws, size_t ws_size,
                              hipStream_t stream) {
    const int*   tok    = (const int*)  d_in[0];
    const float* hidden = (const float*)d_in[1];
    const float* tab2   = (const float*)d_in[2];
    const int*   mul2   = (const int*)  d_in[3];
    const float* tab3   = (const float*)d_in[4];
    const int*   mul3   = (const int*)  d_in[5];
    const float* tab4   = (const float*)d_in[6];
    const int*   mul4   = (const int*)  d_in[7];
    const float* Wq     = (const float*)d_in[8];
    const float* bq     = (const float*)d_in[9];
    const float* Wk     = (const float*)d_in[10];
    const float* bk     = (const float*)d_in[11];
    const float* Wv     = (const float*)d_in[12];
    const float* bv     = (const float*)d_in[13];
    const float* Wo     = (const float*)d_in[14];
    const float* bo     = (const float*)d_in[15];

    float* out      = (float*)d_out;
    float* gate_out = out + (size_t)16384 * 64;   // B*S*D, then gate B*S

    hipLaunchKernelGGL(prep_ws, dim3(100), dim3(256), 0, stream,
                       Wk, Wv, Wq, Wo, (char*)d_ws);
    hipLaunchKernelGGL(engram_main, dim3(512), dim3(256), 0, stream,
                       tok, hidden, tab2, mul2, tab3, mul3, tab4, mul4,
                       bq, bk, bv, bo, (const char*)d_ws, out, gate_out);
}

// Round 10
// 41.256 us; speedup vs baseline: 1.3375x; 1.3375x over previous
//
#include <hip/hip_runtime.h>

#define SEQ  2048
#define NSEG 24
#define HSEG 12

typedef __bf16 bf16x8 __attribute__((ext_vector_type(8)));
typedef float  f32x4  __attribute__((ext_vector_type(4)));
typedef unsigned short u16x4 __attribute__((ext_vector_type(4)));
typedef unsigned short ushort8 __attribute__((ext_vector_type(8)));
typedef unsigned long long u64;

// d_ws layout (bytes): [0,256) zero row; then bf16 B-fragment blocks
#define WS_K 256
#define WS_V (256 + 196608)
#define WS_Q (256 + 393216)
#define WS_O (256 + 393216 + 8192)

__device__ __forceinline__ float4 ld4(const float* __restrict__ p) {
    return *reinterpret_cast<const float4*>(p);
}
__device__ __forceinline__ unsigned short f2bf(float f) {
    unsigned u = __float_as_uint(f);
    unsigned r = u + 0x7FFFu + ((u >> 16) & 1u);   // RNE
    return (unsigned short)(r >> 16);
}

// ---------------- prep: weights -> bf16 B-fragment layout in ws ----------------
__global__ __launch_bounds__(256) void prep_ws(
    const float* __restrict__ Wk, const float* __restrict__ Wv,
    const float* __restrict__ Wq, const float* __restrict__ Wo,
    char* __restrict__ ws)
{
    const int tid = blockIdx.x * 256 + threadIdx.x;
    if (tid < 64) ((float*)ws)[tid] = 0.0f;
    const float* W; char* base; int it = tid;
    if      (it < 12288) { W = Wk; base = ws + WS_K; }
    else if (it < 24576) { W = Wv; base = ws + WS_V; it -= 12288; }
    else if (it < 25088) { W = Wq; base = ws + WS_Q; it -= 24576; }
    else if (it < 25600) { W = Wo; base = ws + WS_O; it -= 25088; }
    else return;
    const int lc = it & 15, lg = (it >> 4) & 3, nt = (it >> 6) & 3, sh = it >> 8;
    const int col = nt * 16 + lc;
    const int k0  = sh * 32 + lg * 8;
    ushort8 v;
#pragma unroll
    for (int j = 0; j < 8; ++j) v[j] = f2bf(W[(size_t)(k0 + j) * 64 + col]);
    *(ushort8*)(base + (size_t)it * 16) = v;
}

// ---------------- main: K-split halves, 26.4KB LDS -> all blocks resident -----
// LDS: A-frags bf16 [12 seg][2048B] = 24576 ; idx[24][16] = 1536 @24576
//      gatep 256 @26112 ; gateL 64 @26368
// epilogue aliases (A region dead): gv bf16 @ L+0 ; out-stage fp32 @ L+4096
#define L_IDX  24576
#define LDS_BYTES 26432

__global__ __launch_bounds__(256, 4) void engram_main(
    const int*   __restrict__ tok,
    const float* __restrict__ hidden,
    const float* __restrict__ tab2, const int* __restrict__ mul2,
    const float* __restrict__ tab3, const int* __restrict__ mul3,
    const float* __restrict__ tab4, const int* __restrict__ mul4,
    const float* __restrict__ bq, const float* __restrict__ bk,
    const float* __restrict__ bv, const float* __restrict__ bo,
    const char*  __restrict__ ws,
    float* __restrict__ out, float* __restrict__ gate_out)
{
    __shared__ __align__(16) char L[LDS_BYTES];
    int*   idxL  = (int*)  (L + L_IDX);
    float* gatep = (float*)(L + L_IDX + 1536);
    float* gateL = (float*)(L + L_IDX + 1792);

    const int t     = threadIdx.x;
    const int pbase = blockIdx.x * 16;

    // ---- hash phase: 128 threads x 3 chains ---------------------------------
    if (t < 128) {
        const int h = t >> 4, r0 = t & 15;
        const int pos = pbase + r0;
        const int s   = pos & (SEQ - 1);
        const int b   = pos >> 11;
        const int* tr = tok + (size_t)b * SEQ;
        const u64 t3 = (u64)tr[s];
        const u64 t2 = (s >= 1) ? (u64)tr[s - 1] : 0ull;
        const u64 t1 = (s >= 2) ? (u64)tr[s - 2] : 0ull;
        const u64 t0 = (s >= 3) ? (u64)tr[s - 3] : 0ull;
        { u64 m = (u64)mul2[h];
          u64 hh = (t2 * m + t3) % 100003ull;
          idxL[h * 16 + r0] = (s >= 1) ? (int)hh : -1; }
        { u64 m = (u64)mul3[h];
          u64 hh = (t1 * m + t2) % 100019ull;
          hh = (hh * m + t3) % 100019ull;
          idxL[(8 + h) * 16 + r0] = (s >= 2) ? (int)hh : -1; }
        { u64 m = (u64)mul4[h];
          u64 hh = (t0 * m + t1) % 100043ull;
          hh = (hh * m + t2) % 100043ull;
          hh = (hh * m + t3) % 100043ull;
          idxL[(16 + h) * 16 + r0] = (s >= 3) ? (int)hh : -1; }
    }
    __syncthreads();

    // ---- gather issue: thread (r = t>>4, c = t&15); both halves up-front ------
    const int r     = t >> 4;
    const int c     = t & 15;
    const int fhalf = c >> 3, flg = (c >> 1) & 3, piece = c & 1;
    const int wb = fhalf * 1024 + flg * 256 + ((r ^ flg) << 4) + piece * 8;

    float4 R0[HSEG], R1[HSEG];
    auto gissue = [&](int base, float4* R) {
#pragma unroll
        for (int sl = 0; sl < HSEG; ++sl) {
            const int s  = base + sl;
            const int ix = idxL[s * 16 + r];
            const int ni = s >> 3, h = s & 7;
            const float* tabp; int prime;
            if (ni == 0)      { tabp = tab2; prime = 100003; }
            else if (ni == 1) { tabp = tab3; prime = 100019; }
            else              { tabp = tab4; prime = 100043; }
            float4 z; z.x = z.y = z.z = z.w = 0.0f;
            R[sl] = (ix < 0) ? z : ld4(tabp + ((size_t)h * prime + ix) * 64 + c * 4);
        }
    };
    auto wbuf = [&](const float4* R) {
#pragma unroll
        for (int sl = 0; sl < HSEG; ++sl) {
            u16x4 e;
            e[0] = f2bf(R[sl].x); e[1] = f2bf(R[sl].y);
            e[2] = f2bf(R[sl].z); e[3] = f2bf(R[sl].w);
            *(u16x4*)(L + sl * 2048 + wb) = e;
        }
    };

    gissue(0,    R0);
    gissue(HSEG, R1);       // half-1 gathers stay in flight across half-0 work

    // ---- compute roles --------------------------------------------------------
    const int w   = t >> 6;
    const int lam = t & 63;
    const int lg  = lam >> 4, lc = lam & 15;
    const int fo  = lg * 256 + lc * 16;
    const int ra  = lg * 256 + (((lc ^ lg) & 15) << 4);
    const int cc  = w * 16 + lc;
    const float bkc = bk[cc], bvc = bv[cc], bqc = bq[cc], boc = bo[cc];

    const char* pK = ws + WS_K;
    const char* pV = ws + WS_V;
#define LOADB(s, k0_, k1_, v0_, v1_)                                          \
    { const char* bk_ = pK + (size_t)(s) * 8192 + w * 1024 + fo;              \
      const char* bv_ = pV + (size_t)(s) * 8192 + w * 1024 + fo;              \
      k0_ = *(const bf16x8*)(bk_);        k1_ = *(const bf16x8*)(bk_ + 4096); \
      v0_ = *(const bf16x8*)(bv_);        v1_ = *(const bf16x8*)(bv_ + 4096); }

    f32x4 kacc = {0.f,0.f,0.f,0.f}, vacc = {0.f,0.f,0.f,0.f};
    float4 h0a, h0b, h1a, h1b;

    // ---- half 0 ---------------------------------------------------------------
    wbuf(R0);                        // counted wait: R1's 12 loads stay in flight
    __syncthreads();
    {
        bf16x8 ck0, ck1, cv0, cv1, nk0, nk1, nv0, nv1;
        LOADB(0, ck0, ck1, cv0, cv1);
        LOADB(1, nk0, nk1, nv0, nv1);

        const float* hp = hidden + (size_t)(pbase + lc) * 64 + lg * 8;
        h0a = ld4(hp);      h0b = ld4(hp + 4);
        h1a = ld4(hp + 32); h1b = ld4(hp + 36);

#pragma unroll
        for (int sl = 0; sl < HSEG; ++sl) {
            const bf16x8 a0 = *(const bf16x8*)(L + sl * 2048 +        ra);
            const bf16x8 a1 = *(const bf16x8*)(L + sl * 2048 + 1024 + ra);
            kacc = __builtin_amdgcn_mfma_f32_16x16x32_bf16(a0, ck0, kacc, 0, 0, 0);
            kacc = __builtin_amdgcn_mfma_f32_16x16x32_bf16(a1, ck1, kacc, 0, 0, 0);
            vacc = __builtin_amdgcn_mfma_f32_16x16x32_bf16(a0, cv0, vacc, 0, 0, 0);
            vacc = __builtin_amdgcn_mfma_f32_16x16x32_bf16(a1, cv1, vacc, 0, 0, 0);
            ck0 = nk0; ck1 = nk1; cv0 = nv0; cv1 = nv1;
            if (sl + 2 < HSEG) LOADB(sl + 2, nk0, nk1, nv0, nv1);
        }
    }
    __syncthreads();                 // all half-0 A reads done

    // ---- half 1 ---------------------------------------------------------------
    wbuf(R1);                        // data long since landed
    __syncthreads();
    {
        bf16x8 ck0, ck1, cv0, cv1, nk0, nk1, nv0, nv1;
        LOADB(HSEG,     ck0, ck1, cv0, cv1);
        LOADB(HSEG + 1, nk0, nk1, nv0, nv1);
#pragma unroll
        for (int sl = 0; sl < HSEG; ++sl) {
            const bf16x8 a0 = *(const bf16x8*)(L + sl * 2048 +        ra);
            const bf16x8 a1 = *(const bf16x8*)(L + sl * 2048 + 1024 + ra);
            kacc = __builtin_amdgcn_mfma_f32_16x16x32_bf16(a0, ck0, kacc, 0, 0, 0);
            kacc = __builtin_amdgcn_mfma_f32_16x16x32_bf16(a1, ck1, kacc, 0, 0, 0);
            vacc = __builtin_amdgcn_mfma_f32_16x16x32_bf16(a0, cv0, vacc, 0, 0, 0);
            vacc = __builtin_amdgcn_mfma_f32_16x16x32_bf16(a1, cv1, vacc, 0, 0, 0);
            ck0 = nk0; ck1 = nk1; cv0 = nv0; cv1 = nv1;
            if (sl + 2 < HSEG) LOADB(HSEG + sl + 2, nk0, nk1, nv0, nv1);
        }
    }

    // ---- epilogue -------------------------------------------------------------
#pragma unroll
    for (int i = 0; i < 4; ++i) { kacc[i] += bkc; vacc[i] += bvc; }

    bf16x8 qa0, qa1;
    qa0[0]=(__bf16)h0a.x; qa0[1]=(__bf16)h0a.y; qa0[2]=(__bf16)h0a.z; qa0[3]=(__bf16)h0a.w;
    qa0[4]=(__bf16)h0b.x; qa0[5]=(__bf16)h0b.y; qa0[6]=(__bf16)h0b.z; qa0[7]=(__bf16)h0b.w;
    qa1[0]=(__bf16)h1a.x; qa1[1]=(__bf16)h1a.y; qa1[2]=(__bf16)h1a.z; qa1[3]=(__bf16)h1a.w;
    qa1[4]=(__bf16)h1b.x; qa1[5]=(__bf16)h1b.y; qa1[6]=(__bf16)h1b.z; qa1[7]=(__bf16)h1b.w;
    f32x4 qacc = {0.f,0.f,0.f,0.f};
    {
        const char* bq_ = ws + WS_Q + w * 1024 + fo;
        const bf16x8 qb0 = *(const bf16x8*)(bq_);
        const bf16x8 qb1 = *(const bf16x8*)(bq_ + 4096);
        qacc = __builtin_amdgcn_mfma_f32_16x16x32_bf16(qa0, qb0, qacc, 0, 0, 0);
        qacc = __builtin_amdgcn_mfma_f32_16x16x32_bf16(qa1, qb1, qacc, 0, 0, 0);
    }
    float gp4[4];
#pragma unroll
    for (int i = 0; i < 4; ++i) {
        float p = (qacc[i] + bqc) * kacc[i];
        p += __shfl_xor(p, 1, 64);
        p += __shfl_xor(p, 2, 64);
        p += __shfl_xor(p, 4, 64);
        p += __shfl_xor(p, 8, 64);
        gp4[i] = p;
    }
    if (lc == 0) {
#pragma unroll
        for (int i = 0; i < 4; ++i) gatep[w * 16 + lg * 4 + i] = gp4[i];
    }
    __syncthreads();                 // A reads done; gatep visible

    if (t < 16) {
        const float s  = gatep[t] + gatep[16 + t] + gatep[32 + t] + gatep[48 + t];
        const float gt = 1.0f / (1.0f + expf(-s * 0.125f));
        gateL[t] = gt;
        gate_out[pbase + t] = gt;
    }
    __syncthreads();                 // gate visible; A region free

    char*  Lgv  = L;
    float* Lout = (float*)(L + 4096);

    // gv = gate * v (bf16, XOR-swizzled) into A region
#pragma unroll
    for (int i = 0; i < 4; ++i) {
        const int row = lg * 4 + i;
        const float gvv = gateL[row] * vacc[i];
        *(unsigned short*)(Lgv + row * 128 + ((w * 32 + lc * 2) ^ ((row & 7) << 4))) = f2bf(gvv);
    }
    __syncthreads();

    // out = gv @ Wo + bo -> stage fp32 in LDS, coalesced store
    f32x4 oacc = {0.f,0.f,0.f,0.f};
    {
        const char* bo_ = ws + WS_O + w * 1024 + fo;
        const bf16x8 ob0 = *(const bf16x8*)(bo_);
        const bf16x8 ob1 = *(const bf16x8*)(bo_ + 4096);
        const bf16x8 ga0 = *(const bf16x8*)(Lgv + lc * 128 + ((lg * 16)      ^ ((lc & 7) << 4)));
        const bf16x8 ga1 = *(const bf16x8*)(Lgv + lc * 128 + ((64 + lg * 16) ^ ((lc & 7) << 4)));
        oacc = __builtin_amdgcn_mfma_f32_16x16x32_bf16(ga0, ob0, oacc, 0, 0, 0);
        oacc = __builtin_amdgcn_mfma_f32_16x16x32_bf16(ga1, ob1, oacc, 0, 0, 0);
    }
#pragma unroll
    for (int i = 0; i < 4; ++i)
        Lout[(lg * 4 + i) * 64 + cc] = oacc[i] + boc;
    __syncthreads();

    {
        const float4 o4 = *(const float4*)(Lout + r * 64 + c * 4);
        *reinterpret_cast<float4*>(out + (size_t)(pbase + r) * 64 + c * 4) = o4;
    }
}

extern "C" void kernel_launch(void* const* d_in, const int* in_sizes, int n_in,
                              void* d_out, int out_size, void* d_ws, size_t ws_size,
                              hipStream_t stream) {
    const int*   tok    = (const int*)  d_in[0];
    const float* hidden = (const float*)d_in[1];
    const float* tab2   = (const float*)d_in[2];
    const int*   mul2   = (const int*)  d_in[3];
    const float* tab3   = (const float*)d_in[4];
    const int*   mul3   = (const int*)  d_in[5];
    const float* tab4   = (const float*)d_in[6];
    const int*   mul4   = (const int*)  d_in[7];
    const float* Wq     = (const float*)d_in[8];
    const float* bq     = (const float*)d_in[9];
    const float* Wk     = (const float*)d_in[10];
    const float* bk     = (const float*)d_in[11];
    const float* Wv     = (const float*)d_in[12];
    const float* bv     = (const float*)d_in[13];
    const float* Wo     = (const float*)d_in[14];
    const float* bo     = (const float*)d_in[15];

    float* out      = (float*)d_out;
    float* gate_out = out + (size_t)16384 * 64;   // B*S*D, then gate B*S

    hipLaunchKernelGGL(prep_ws, dim3(100), dim3(256), 0, stream,
                       Wk, Wv, Wq, Wo, (char*)d_ws);
    hipLaunchKernelGGL(engram_main, dim3(16384 / 16), dim3(256), 0, stream,
                       tok, hidden, tab2, mul2, tab3, mul3, tab4, mul4,
                       bq, bk, bv, bo, (const char*)d_ws, out, gate_out);
}

// Round 11
// 40.101 us; speedup vs baseline: 1.3760x; 1.0288x over previous
//
#include <hip/hip_runtime.h>

#define SEQ  2048
#define NSEG 24

typedef __bf16 bf16x8 __attribute__((ext_vector_type(8)));
typedef float  f32x4  __attribute__((ext_vector_type(4)));
typedef unsigned short u16x4 __attribute__((ext_vector_type(4)));
typedef unsigned short ushort8 __attribute__((ext_vector_type(8)));
typedef unsigned long long u64;

// d_ws layout (bytes): [0,256) zero row; then bf16 B-fragment blocks
#define WS_K 256
#define WS_V (256 + 196608)
#define WS_Q (256 + 393216)
#define WS_O (256 + 393216 + 8192)

__device__ __forceinline__ float4 ld4(const float* __restrict__ p) {
    return *reinterpret_cast<const float4*>(p);
}
__device__ __forceinline__ unsigned short f2bf(float f) {
    unsigned u = __float_as_uint(f);
    unsigned r = u + 0x7FFFu + ((u >> 16) & 1u);   // RNE
    return (unsigned short)(r >> 16);
}

// ---------------- prep: weights -> bf16 B-fragment layout in ws ----------------
__global__ __launch_bounds__(256) void prep_ws(
    const float* __restrict__ Wk, const float* __restrict__ Wv,
    const float* __restrict__ Wq, const float* __restrict__ Wo,
    char* __restrict__ ws)
{
    const int tid = blockIdx.x * 256 + threadIdx.x;
    if (tid < 64) ((float*)ws)[tid] = 0.0f;
    const float* W; char* base; int it = tid;
    if      (it < 12288) { W = Wk; base = ws + WS_K; }
    else if (it < 24576) { W = Wv; base = ws + WS_V; it -= 12288; }
    else if (it < 25088) { W = Wq; base = ws + WS_Q; it -= 24576; }
    else if (it < 25600) { W = Wo; base = ws + WS_O; it -= 25088; }
    else return;
    const int lc = it & 15, lg = (it >> 4) & 3, nt = (it >> 6) & 3, sh = it >> 8;
    const int col = nt * 16 + lc;
    const int k0  = sh * 32 + lg * 8;
    ushort8 v;
#pragma unroll
    for (int j = 0; j < 8; ++j) v[j] = f2bf(W[(size_t)(k0 + j) * 64 + col]);
    *(ushort8*)(base + (size_t)it * 16) = v;
}

// ---------------- main: whole-tile gather, then clean MFMA sweep --------------
// LDS: A-frags bf16 [24 seg][2 half][64 slot x16B] (slot-swizzled) 49152
//      idx[24][16] 1536 (aliased later: gatep 256 + gateL 64)
// epilogue aliases (A region dead after compute + barrier):
//      gv bf16 @ L+0 (2048) ; out-stage fp32 [16][64] @ L+4096 (4096)
#define L_IDX  49152
#define LDS_BYTES 50688

__global__ __launch_bounds__(256, 3) void engram_main(
    const int*   __restrict__ tok,
    const float* __restrict__ hidden,
    const float* __restrict__ tab2, const int* __restrict__ mul2,
    const float* __restrict__ tab3, const int* __restrict__ mul3,
    const float* __restrict__ tab4, const int* __restrict__ mul4,
    const float* __restrict__ bq, const float* __restrict__ bk,
    const float* __restrict__ bv, const float* __restrict__ bo,
    const char*  __restrict__ ws,
    float* __restrict__ out, float* __restrict__ gate_out)
{
    __shared__ __align__(16) char L[LDS_BYTES];
    int*   idxL  = (int*)  (L + L_IDX);
    float* gatep = (float*)(L + L_IDX);          // alias: idx dead after gather
    float* gateL = (float*)(L + L_IDX + 256);
    char*  Lgv   = L;                            // alias: A region, post-barrier
    float* Lout  = (float*)(L + 4096);           // alias: A region, post-barrier

    const int t     = threadIdx.x;
    const int pbase = blockIdx.x * 16;

    // ---- hash phase: 128 threads x 3 chains ---------------------------------
    if (t < 128) {
        const int h = t >> 4, r0 = t & 15;
        const int pos = pbase + r0;
        const int s   = pos & (SEQ - 1);
        const int b   = pos >> 11;
        const int* tr = tok + (size_t)b * SEQ;
        const u64 t3 = (u64)tr[s];
        const u64 t2 = (s >= 1) ? (u64)tr[s - 1] : 0ull;
        const u64 t1 = (s >= 2) ? (u64)tr[s - 2] : 0ull;
        const u64 t0 = (s >= 3) ? (u64)tr[s - 3] : 0ull;
        { u64 m = (u64)mul2[h];
          u64 hh = (t2 * m + t3) % 100003ull;
          idxL[h * 16 + r0] = (s >= 1) ? (int)hh : -1; }
        { u64 m = (u64)mul3[h];
          u64 hh = (t1 * m + t2) % 100019ull;
          hh = (hh * m + t3) % 100019ull;
          idxL[(8 + h) * 16 + r0] = (s >= 2) ? (int)hh : -1; }
        { u64 m = (u64)mul4[h];
          u64 hh = (t0 * m + t1) % 100043ull;
          hh = (hh * m + t2) % 100043ull;
          hh = (hh * m + t3) % 100043ull;
          idxL[(16 + h) * 16 + r0] = (s >= 3) ? (int)hh : -1; }
    }
    __syncthreads();

    // ---- gather phase: thread = (row r = t>>4, chunk c = t&15); iter = seg ----
    const int r     = t >> 4;
    const int c     = t & 15;
    const int fhalf = c >> 3, flg = (c >> 1) & 3, piece = c & 1;
    const int wb = fhalf * 1024 + flg * 256 + ((r ^ flg) << 4) + piece * 8;

    float4 R[NSEG];
#pragma unroll
    for (int s = 0; s < NSEG; ++s) {               // 24 independent loads
        const int ix = idxL[s * 16 + r];
        const int ni = s >> 3, h = s & 7;
        const float* tabp; int prime;
        if (ni == 0)      { tabp = tab2; prime = 100003; }
        else if (ni == 1) { tabp = tab3; prime = 100019; }
        else              { tabp = tab4; prime = 100043; }
        float4 z; z.x = z.y = z.z = z.w = 0.0f;
        R[s] = (ix < 0) ? z : ld4(tabp + ((size_t)h * prime + ix) * 64 + c * 4);
    }
#pragma unroll
    for (int s = 0; s < NSEG; ++s) {               // cvt + LDS store (conflict-free)
        u16x4 e;
        e[0] = f2bf(R[s].x); e[1] = f2bf(R[s].y);
        e[2] = f2bf(R[s].z); e[3] = f2bf(R[s].w);
        *(u16x4*)(L + s * 2048 + wb) = e;
    }
    __syncthreads();

    // ---- compute phase: wave w owns output cols w*16..+15, full K -------------
    const int w   = t >> 6;
    const int lam = t & 63;
    const int lg  = lam >> 4, lc = lam & 15;
    const int fo  = lg * 256 + lc * 16;                       // ws B-frag offset
    const int ra  = lg * 256 + (((lc ^ lg) & 15) << 4);       // swizzled A-slot read

    const char* pK = ws + WS_K;
    const char* pV = ws + WS_V;
#define LOADB(s, k0_, k1_, v0_, v1_)                                     \
    { const char* bk_ = pK + (size_t)(s) * 8192 + w * 1024 + fo;         \
      const char* bv_ = pV + (size_t)(s) * 8192 + w * 1024 + fo;         \
      k0_ = *(const bf16x8*)(bk_);        k1_ = *(const bf16x8*)(bk_ + 4096); \
      v0_ = *(const bf16x8*)(bv_);        v1_ = *(const bf16x8*)(bv_ + 4096); }

    f32x4 kacc = {0.f,0.f,0.f,0.f}, vacc = {0.f,0.f,0.f,0.f};
    bf16x8 ck0, ck1, cv0, cv1, nk0, nk1, nv0, nv1;
    LOADB(0, ck0, ck1, cv0, cv1);
    LOADB(1, nk0, nk1, nv0, nv1);

    // hidden for q (issued after first B loads so B waits stay counted)
    const float* hp = hidden + (size_t)(pbase + lc) * 64 + lg * 8;
    const float4 h0a = ld4(hp),      h0b = ld4(hp + 4);
    const float4 h1a = ld4(hp + 32), h1b = ld4(hp + 36);

#pragma unroll
    for (int s = 0; s < NSEG; ++s) {
        const bf16x8 a0 = *(const bf16x8*)(L + s * 2048 +        ra);
        const bf16x8 a1 = *(const bf16x8*)(L + s * 2048 + 1024 + ra);
        kacc = __builtin_amdgcn_mfma_f32_16x16x32_bf16(a0, ck0, kacc, 0, 0, 0);
        kacc = __builtin_amdgcn_mfma_f32_16x16x32_bf16(a1, ck1, kacc, 0, 0, 0);
        vacc = __builtin_amdgcn_mfma_f32_16x16x32_bf16(a0, cv0, vacc, 0, 0, 0);
        vacc = __builtin_amdgcn_mfma_f32_16x16x32_bf16(a1, cv1, vacc, 0, 0, 0);
        ck0 = nk0; ck1 = nk1; cv0 = nv0; cv1 = nv1;
        if (s + 2 < NSEG) LOADB(s + 2, nk0, nk1, nv0, nv1);
    }

    // ---- epilogue -------------------------------------------------------------
    const int   cc  = w * 16 + lc;
    const float bkc = bk[cc], bvc = bv[cc], bqc = bq[cc], boc = bo[cc];
#pragma unroll
    for (int i = 0; i < 4; ++i) { kacc[i] += bkc; vacc[i] += bvc; }

    // q = hidden @ Wq (this wave's quarter)
    bf16x8 qa0, qa1;
    qa0[0]=(__bf16)h0a.x; qa0[1]=(__bf16)h0a.y; qa0[2]=(__bf16)h0a.z; qa0[3]=(__bf16)h0a.w;
    qa0[4]=(__bf16)h0b.x; qa0[5]=(__bf16)h0b.y; qa0[6]=(__bf16)h0b.z; qa0[7]=(__bf16)h0b.w;
    qa1[0]=(__bf16)h1a.x; qa1[1]=(__bf16)h1a.y; qa1[2]=(__bf16)h1a.z; qa1[3]=(__bf16)h1a.w;
    qa1[4]=(__bf16)h1b.x; qa1[5]=(__bf16)h1b.y; qa1[6]=(__bf16)h1b.z; qa1[7]=(__bf16)h1b.w;
    f32x4 qacc = {0.f,0.f,0.f,0.f};
    {
        const char* bq_ = ws + WS_Q + w * 1024 + fo;
        const bf16x8 qb0 = *(const bf16x8*)(bq_);
        const bf16x8 qb1 = *(const bf16x8*)(bq_ + 4096);
        qacc = __builtin_amdgcn_mfma_f32_16x16x32_bf16(qa0, qb0, qacc, 0, 0, 0);
        qacc = __builtin_amdgcn_mfma_f32_16x16x32_bf16(qa1, qb1, qacc, 0, 0, 0);
    }
    float gp4[4];
#pragma unroll
    for (int i = 0; i < 4; ++i) {
        float p = (qacc[i] + bqc) * kacc[i];
        p += __shfl_xor(p, 1, 64);
        p += __shfl_xor(p, 2, 64);
        p += __shfl_xor(p, 4, 64);
        p += __shfl_xor(p, 8, 64);
        gp4[i] = p;
    }
    if (lc == 0) {
#pragma unroll
        for (int i = 0; i < 4; ++i) gatep[w * 16 + lg * 4 + i] = gp4[i];
    }
    __syncthreads();                 // bar A: all A-frag reads done; gatep visible

    if (t < 16) {
        const float s  = gatep[t] + gatep[16 + t] + gatep[32 + t] + gatep[48 + t];
        const float gt = 1.0f / (1.0f + expf(-s * 0.125f));
        gateL[t] = gt;
        gate_out[pbase + t] = gt;
    }
    __syncthreads();                 // bar B: gate visible; A region free

    // gv = gate * v  (bf16 [16][64], XOR-swizzled) into A region
#pragma unroll
    for (int i = 0; i < 4; ++i) {
        const int row = lg * 4 + i;
        const float gvv = gateL[row] * vacc[i];
        *(unsigned short*)(Lgv + row * 128 + ((w * 32 + lc * 2) ^ ((row & 7) << 4))) = f2bf(gvv);
    }
    __syncthreads();                 // bar C

    // out = gv @ Wo + bo (this wave's quarter) -> stage fp32 in LDS
    f32x4 oacc = {0.f,0.f,0.f,0.f};
    {
        const char* bo_ = ws + WS_O + w * 1024 + fo;
        const bf16x8 ob0 = *(const bf16x8*)(bo_);
        const bf16x8 ob1 = *(const bf16x8*)(bo_ + 4096);
        const bf16x8 ga0 = *(const bf16x8*)(Lgv + lc * 128 + ((lg * 16)      ^ ((lc & 7) << 4)));
        const bf16x8 ga1 = *(const bf16x8*)(Lgv + lc * 128 + ((64 + lg * 16) ^ ((lc & 7) << 4)));
        oacc = __builtin_amdgcn_mfma_f32_16x16x32_bf16(ga0, ob0, oacc, 0, 0, 0);
        oacc = __builtin_amdgcn_mfma_f32_16x16x32_bf16(ga1, ob1, oacc, 0, 0, 0);
    }
#pragma unroll
    for (int i = 0; i < 4; ++i)
        Lout[(lg * 4 + i) * 64 + cc] = oacc[i] + boc;
    __syncthreads();                 // bar D

    // coalesced store: thread (r, c) writes float4 -> full 256B rows per wave
    {
        const float4 o4 = *(const float4*)(Lout + r * 64 + c * 4);
        *reinterpret_cast<float4*>(out + (size_t)(pbase + r) * 64 + c * 4) = o4;
    }
}

extern "C" void kernel_launch(void* const* d_in, const int* in_sizes, int n_in,
                              void* d_out, int out_size, void* d_ws, size_t ws_size,
                              hipStream_t stream) {
    const int*   tok    = (const int*)  d_in[0];
    const float* hidden = (const float*)d_in[1];
    const float* tab2   = (const float*)d_in[2];
    const int*   mul2   = (const int*)  d_in[3];
    const float* tab3   = (const float*)d_in[4];
    const int*   mul3   = (const int*)  d_in[5];
    const float* tab4   = (const float*)d_in[6];
    const int*   mul4   = (const int*)  d_in[7];
    const float* Wq     = (const float*)d_in[8];
    const float* bq     = (const float*)d_in[9];
    const float* Wk     = (const float*)d_in[10];
    const float* bk     = (const float*)d_in[11];
    const float* Wv     = (const float*)d_in[12];
    const float* bv     = (const float*)d_in[13];
    const float* Wo     = (const float*)d_in[14];
    const float* bo     = (const float*)d_in[15];

    float* out      = (float*)d_out;
    float* gate_out = out + (size_t)16384 * 64;   // B*S*D, then gate B*S

    hipLaunchKernelGGL(prep_ws, dim3(100), dim3(256), 0, stream,
                       Wk, Wv, Wq, Wo, (char*)d_ws);
    hipLaunchKernelGGL(engram_main, dim3(16384 / 16), dim3(256), 0, stream,
                       tok, hidden, tab2, mul2, tab3, mul3, tab4, mul4,
                       bq, bk, bv, bo, (const char*)d_ws, out, gate_out);
}